// Round 9
// baseline (112.178 us; speedup 1.0000x reference)
//
#include <hip/hip_runtime.h>
#include <hip/hip_fp16.h>
#include <math.h>

#define IN_CH 32
#define K_OUT 4
#define PREP_TILE 64   // nodes per block in prep

typedef _Float16 h2_t __attribute__((ext_vector_type(2)));

// fp16x2 dot with fp32 accumulate: uses v_dot2_f32_f16 when available.
__device__ __forceinline__ float dot2acc(unsigned int a, unsigned int b, float c) {
#if defined(__has_builtin)
#if __has_builtin(__builtin_amdgcn_fdot2)
    return __builtin_amdgcn_fdot2(__builtin_bit_cast(h2_t, a),
                                  __builtin_bit_cast(h2_t, b), c, false);
#else
    __half2 ha = *(__half2*)&a, hb = *(__half2*)&b;
    float2 fa = __half22float2(ha), fb = __half22float2(hb);
    return fmaf(fa.y, fb.y, fmaf(fa.x, fb.x, c));
#endif
#else
    __half2 ha = *(__half2*)&a, hb = *(__half2*)&b;
    float2 fa = __half22float2(ha), fb = __half22float2(hb);
    return fmaf(fa.y, fb.y, fmaf(fa.x, fb.x, c));
#endif
}

// ---------------------------------------------------------------------------
// Prep v3: block = 64 CONTIGUOUS nodes.
// Phase 1: stream x -> x16 (coalesced float4 loads, 8B half4 stores); this
//          also warms L1 with the block's whole x tile (16 KB < 32 KB L1).
// Phase 2: lane ki (=tid&127) computes z16[n][ki] for its half of the tile,
//          reading x rows as uniform float4 (L1-hot) and T from 32 VGPRs.
// No LDS, no divergent scalar writes, contiguous-node streaming.
// ---------------------------------------------------------------------------
__global__ __launch_bounds__(256)
void prep_kernel(const float* __restrict__ x,
                 const float* __restrict__ T,
                 __half* __restrict__ z16,
                 __half* __restrict__ x16,
                 int n_nodes) {
    const int tid = threadIdx.x;
    const int tile0 = blockIdx.x * PREP_TILE;
    const long long ftotal = (long long)n_nodes * IN_CH;

    // ---- phase 1: x16 convert, fully coalesced (2 x float4 per thread) ----
    const long long fbase = (long long)tile0 * IN_CH;
#pragma unroll
    for (int r = 0; r < 2; ++r) {
        long long fi = fbase + (long long)r * 1024 + (long long)tid * 4;
        if (fi + 3 < ftotal) {
            float4 v = *(const float4*)(x + fi);
            __half2 h0 = __floats2half2_rn(v.x, v.y);
            __half2 h1 = __floats2half2_rn(v.z, v.w);
            uint2 pack;
            pack.x = *(unsigned int*)&h0;
            pack.y = *(unsigned int*)&h1;
            *(uint2*)(x16 + fi) = pack;
        } else if (fi < ftotal) {
            for (long long q = fi; q < ftotal; ++q)
                x16[q] = __float2half(x[q]);
        }
    }

    // ---- T row in registers (lane-varying, loaded once) ----
    const int ki = tid & 127;            // k = ki>>5, i = ki&31
    const float4* Tr = (const float4*)(T + (size_t)ki * IN_CH);
    float4 t0 = Tr[0], t1 = Tr[1], t2 = Tr[2], t3 = Tr[3];
    float4 t4 = Tr[4], t5 = Tr[5], t6 = Tr[6], t7 = Tr[7];

    // ---- phase 2: z16 for my half of the tile (x rows L1-hot) ----
    const int half = tid >> 7;           // 0 or 1
    const int n0 = tile0 + half * (PREP_TILE / 2);
#pragma unroll 2
    for (int m = 0; m < PREP_TILE / 2; ++m) {
        const int n = n0 + m;
        if (n >= n_nodes) break;
        const float4* xr = (const float4*)(x + (size_t)n * IN_CH);
        float4 x0 = xr[0], x1 = xr[1], x2 = xr[2], x3 = xr[3];
        float4 x4 = xr[4], x5 = xr[5], x6 = xr[6], x7 = xr[7];

        float a0 = 0.f, a1 = 0.f, a2 = 0.f, a3 = 0.f;
        a0 = fmaf(t0.x, x0.x, a0); a1 = fmaf(t0.y, x0.y, a1);
        a2 = fmaf(t0.z, x0.z, a2); a3 = fmaf(t0.w, x0.w, a3);
        a0 = fmaf(t1.x, x1.x, a0); a1 = fmaf(t1.y, x1.y, a1);
        a2 = fmaf(t1.z, x1.z, a2); a3 = fmaf(t1.w, x1.w, a3);
        a0 = fmaf(t2.x, x2.x, a0); a1 = fmaf(t2.y, x2.y, a1);
        a2 = fmaf(t2.z, x2.z, a2); a3 = fmaf(t2.w, x2.w, a3);
        a0 = fmaf(t3.x, x3.x, a0); a1 = fmaf(t3.y, x3.y, a1);
        a2 = fmaf(t3.z, x3.z, a2); a3 = fmaf(t3.w, x3.w, a3);
        a0 = fmaf(t4.x, x4.x, a0); a1 = fmaf(t4.y, x4.y, a1);
        a2 = fmaf(t4.z, x4.z, a2); a3 = fmaf(t4.w, x4.w, a3);
        a0 = fmaf(t5.x, x5.x, a0); a1 = fmaf(t5.y, x5.y, a1);
        a2 = fmaf(t5.z, x5.z, a2); a3 = fmaf(t5.w, x5.w, a3);
        a0 = fmaf(t6.x, x6.x, a0); a1 = fmaf(t6.y, x6.y, a1);
        a2 = fmaf(t6.z, x6.z, a2); a3 = fmaf(t6.w, x6.w, a3);
        a0 = fmaf(t7.x, x7.x, a0); a1 = fmaf(t7.y, x7.y, a1);
        a2 = fmaf(t7.z, x7.z, a2); a3 = fmaf(t7.w, x7.w, a3);

        z16[(size_t)n * (K_OUT * IN_CH) + ki] = __float2half((a0 + a1) + (a2 + a3));
    }
}

// ---------------------------------------------------------------------------
// Main edge kernel: quad per edge, fp16 operands, fp32 accumulate.
// Per edge (whole quad): idx broadcast + 64B x16 row (1 line) + 256B z16 row
// (4 lines) + coalesced 16B fp32 store.
// NT hints: idx loads (no reuse past one wave) and out stores (write-once)
// bypass/stream L2 so the 16MB gather working set keeps its residency.
// ---------------------------------------------------------------------------
__global__ __launch_bounds__(256)
void edge_kernel_quad16(const __half* __restrict__ x16,
                        const __half* __restrict__ z16,
                        const int* __restrict__ src,
                        const int* __restrict__ dst,
                        float* __restrict__ out,
                        int n_edges) {
    const int t = blockIdx.x * blockDim.x + threadIdx.x;
    const int e = t >> 2;
    const int l = t & 3;
    if (e >= n_edges) return;

    const int s = __builtin_nontemporal_load(src + e);
    const int d = __builtin_nontemporal_load(dst + e);

    // x row = 32 halves = 4 uint4; lane takes uint4 #l (8 halves)
    const uint4 xv = ((const uint4*)x16)[(size_t)s * 4 + l];
    // z row = 128 halves = 16 uint4; slab k at uint4 [4k,4k+4); lane takes +l
    const uint4* zrow = (const uint4*)z16 + (size_t)d * 16;
    const uint4 z0 = zrow[0 + l];
    const uint4 z1 = zrow[4 + l];
    const uint4 z2 = zrow[8 + l];
    const uint4 z3 = zrow[12 + l];

    float p0 = 0.f, p1 = 0.f, p2 = 0.f, p3 = 0.f;
    p0 = dot2acc(xv.x, z0.x, p0); p0 = dot2acc(xv.y, z0.y, p0);
    p0 = dot2acc(xv.z, z0.z, p0); p0 = dot2acc(xv.w, z0.w, p0);

    p1 = dot2acc(xv.x, z1.x, p1); p1 = dot2acc(xv.y, z1.y, p1);
    p1 = dot2acc(xv.z, z1.z, p1); p1 = dot2acc(xv.w, z1.w, p1);

    p2 = dot2acc(xv.x, z2.x, p2); p2 = dot2acc(xv.y, z2.y, p2);
    p2 = dot2acc(xv.z, z2.z, p2); p2 = dot2acc(xv.w, z2.w, p2);

    p3 = dot2acc(xv.x, z3.x, p3); p3 = dot2acc(xv.y, z3.y, p3);
    p3 = dot2acc(xv.z, z3.z, p3); p3 = dot2acc(xv.w, z3.w, p3);

    // Quad transpose-reduce: lane l ends with full maps[e][l].
    float send01 = (l & 1) ? p0 : p1;
    float recv01 = __shfl_xor(send01, 1);
    float a01 = ((l & 1) ? p1 : p0) + recv01;
    float send23 = (l & 1) ? p2 : p3;
    float recv23 = __shfl_xor(send23, 1);
    float a23 = ((l & 1) ? p3 : p2) + recv23;
    float send = (l & 2) ? a01 : a23;
    float recv = __shfl_xor(send, 2);
    float r = ((l & 2) ? a23 : a01) + recv;

    __builtin_nontemporal_store(tanhf(r), out + t);   // coalesced 4B/lane
}

// ---------------------------------------------------------------------------
// Fallback: direct quadratic form per edge (no workspace).
// ---------------------------------------------------------------------------
__global__ void edge_direct_kernel(const float* __restrict__ x,
                                   const float* __restrict__ T,
                                   const int* __restrict__ src,
                                   const int* __restrict__ dst,
                                   float* __restrict__ out,
                                   int n_edges) {
    int e = blockIdx.x * blockDim.x + threadIdx.x;
    if (e >= n_edges) return;

    const int s = src[e];
    const int d = dst[e];

    float xs[IN_CH], xd[IN_CH];
#pragma unroll
    for (int j = 0; j < IN_CH; ++j) {
        xs[j] = x[(size_t)s * IN_CH + j];
        xd[j] = x[(size_t)d * IN_CH + j];
    }

    float resv[K_OUT];
#pragma unroll
    for (int k = 0; k < K_OUT; ++k) {
        float acc = 0.f;
        for (int i = 0; i < IN_CH; ++i) {
            const float* Trow = T + ((size_t)k * IN_CH + i) * IN_CH;
            float yi = 0.f;
#pragma unroll
            for (int j = 0; j < IN_CH; ++j)
                yi = fmaf(Trow[j], xd[j], yi);
            acc = fmaf(xs[i], yi, acc);
        }
        resv[k] = tanhf(acc);
    }
    ((float4*)out)[e] = make_float4(resv[0], resv[1], resv[2], resv[3]);
}

extern "C" void kernel_launch(void* const* d_in, const int* in_sizes, int n_in,
                              void* d_out, int out_size, void* d_ws, size_t ws_size,
                              hipStream_t stream) {
    const float* x  = (const float*)d_in[0];
    const int*   ei = (const int*)d_in[1];
    const float* T  = (const float*)d_in[2];
    float* out      = (float*)d_out;

    const int n_nodes = in_sizes[0] / IN_CH;
    const int n_edges = in_sizes[1] / 2;
    const int* src = ei;
    const int* dst = ei + n_edges;

    // Workspace: z16 then x16 (both 256B-aligned)
    const size_t z16_bytes = (size_t)n_nodes * K_OUT * IN_CH * sizeof(__half);
    const size_t x16_off   = (z16_bytes + 255) & ~(size_t)255;
    const size_t need      = x16_off + (size_t)n_nodes * IN_CH * sizeof(__half);

    const int threads = 256;

    if (ws_size >= need) {
        __half* z16 = (__half*)d_ws;
        __half* x16 = (__half*)((char*)d_ws + x16_off);

        const int pblocks = (n_nodes + PREP_TILE - 1) / PREP_TILE;
        prep_kernel<<<pblocks, 256, 0, stream>>>(x, T, z16, x16, n_nodes);

        const long long total = (long long)n_edges * 4;
        const int blocks = (int)((total + threads - 1) / threads);
        edge_kernel_quad16<<<blocks, threads, 0, stream>>>(
            x16, z16, src, dst, out, n_edges);
    } else {
        const int eblocks = (n_edges + threads - 1) / threads;
        edge_direct_kernel<<<eblocks, threads, 0, stream>>>(x, T, src, dst, out, n_edges);
    }
}

// Round 10
// 102.162 us; speedup vs baseline: 1.0980x; 1.0980x over previous
//
#include <hip/hip_runtime.h>
#include <hip/hip_fp16.h>
#include <math.h>

#define IN_CH 32
#define K_OUT 4

typedef _Float16 h2_t __attribute__((ext_vector_type(2)));

// fp16x2 dot with fp32 accumulate: uses v_dot2_f32_f16 when available.
__device__ __forceinline__ float dot2acc(unsigned int a, unsigned int b, float c) {
#if defined(__has_builtin)
#if __has_builtin(__builtin_amdgcn_fdot2)
    return __builtin_amdgcn_fdot2(__builtin_bit_cast(h2_t, a),
                                  __builtin_bit_cast(h2_t, b), c, false);
#else
    __half2 ha = *(__half2*)&a, hb = *(__half2*)&b;
    float2 fa = __half22float2(ha), fb = __half22float2(hb);
    return fmaf(fa.y, fb.y, fmaf(fa.x, fb.x, c));
#endif
#else
    __half2 ha = *(__half2*)&a, hb = *(__half2*)&b;
    float2 fa = __half22float2(ha), fb = __half22float2(hb);
    return fmaf(fa.y, fb.y, fmaf(fa.x, fb.x, c));
#endif
}

// ---------------------------------------------------------------------------
// prep_z v4: ONE WAVE PER NODE (grid-stride over waves).
// Lane l computes z[n][2l] and z[n][2l+1]; T rows 2l,2l+1 persist in 64 VGPRs.
// x row = 8 uniform float4 loads with MANUAL 1-DEEP PREFETCH: row n+stride is
// issued before computing row n, so the ~300cy L2 latency hides under the
// 64-FMA compute (r8/r9 lesson: unpipelined row loads serialize, 23-46us).
// Store: lane l writes half2 at z16[n*128+2l] -> 256B/wave coalesced.
// ---------------------------------------------------------------------------
__global__ __launch_bounds__(256)
void prep_z_kernel(const float* __restrict__ x,
                   const float* __restrict__ T,
                   __half* __restrict__ z16,
                   int n_nodes, int total_waves) {
    const int wid = (blockIdx.x * blockDim.x + threadIdx.x) >> 6;
    const int l   = threadIdx.x & 63;

    // Persistent T rows (lane-varying addresses, coalesced pairs).
    const float4* Ta = (const float4*)(T + (size_t)(2 * l) * IN_CH);
    const float4* Tb = (const float4*)(T + (size_t)(2 * l + 1) * IN_CH);
    float4 ta0 = Ta[0], ta1 = Ta[1], ta2 = Ta[2], ta3 = Ta[3];
    float4 ta4 = Ta[4], ta5 = Ta[5], ta6 = Ta[6], ta7 = Ta[7];
    float4 tb0 = Tb[0], tb1 = Tb[1], tb2 = Tb[2], tb3 = Tb[3];
    float4 tb4 = Tb[4], tb5 = Tb[5], tb6 = Tb[6], tb7 = Tb[7];

    int n = wid;
    if (n >= n_nodes) return;

    // preload first row
    const float4* xr = (const float4*)(x + (size_t)n * IN_CH);
    float4 c0 = xr[0], c1 = xr[1], c2 = xr[2], c3 = xr[3];
    float4 c4 = xr[4], c5 = xr[5], c6 = xr[6], c7 = xr[7];

    for (;;) {
        const int nn = n + total_waves;
        const bool has = nn < n_nodes;
        // issue next-row loads BEFORE computing current (prefetch)
        const float4* xp = (const float4*)(x + (size_t)(has ? nn : n) * IN_CH);
        float4 p0 = xp[0], p1 = xp[1], p2 = xp[2], p3 = xp[3];
        float4 p4 = xp[4], p5 = xp[5], p6 = xp[6], p7 = xp[7];

        // two dot products, 2 accumulators each (shorter chains)
        float ua = 0.f, ub = 0.f, va = 0.f, vb = 0.f;
        ua = fmaf(ta0.x, c0.x, ua); ub = fmaf(ta0.y, c0.y, ub);
        ua = fmaf(ta0.z, c0.z, ua); ub = fmaf(ta0.w, c0.w, ub);
        ua = fmaf(ta1.x, c1.x, ua); ub = fmaf(ta1.y, c1.y, ub);
        ua = fmaf(ta1.z, c1.z, ua); ub = fmaf(ta1.w, c1.w, ub);
        ua = fmaf(ta2.x, c2.x, ua); ub = fmaf(ta2.y, c2.y, ub);
        ua = fmaf(ta2.z, c2.z, ua); ub = fmaf(ta2.w, c2.w, ub);
        ua = fmaf(ta3.x, c3.x, ua); ub = fmaf(ta3.y, c3.y, ub);
        ua = fmaf(ta3.z, c3.z, ua); ub = fmaf(ta3.w, c3.w, ub);
        ua = fmaf(ta4.x, c4.x, ua); ub = fmaf(ta4.y, c4.y, ub);
        ua = fmaf(ta4.z, c4.z, ua); ub = fmaf(ta4.w, c4.w, ub);
        ua = fmaf(ta5.x, c5.x, ua); ub = fmaf(ta5.y, c5.y, ub);
        ua = fmaf(ta5.z, c5.z, ua); ub = fmaf(ta5.w, c5.w, ub);
        ua = fmaf(ta6.x, c6.x, ua); ub = fmaf(ta6.y, c6.y, ub);
        ua = fmaf(ta6.z, c6.z, ua); ub = fmaf(ta6.w, c6.w, ub);
        ua = fmaf(ta7.x, c7.x, ua); ub = fmaf(ta7.y, c7.y, ub);
        ua = fmaf(ta7.z, c7.z, ua); ub = fmaf(ta7.w, c7.w, ub);

        va = fmaf(tb0.x, c0.x, va); vb = fmaf(tb0.y, c0.y, vb);
        va = fmaf(tb0.z, c0.z, va); vb = fmaf(tb0.w, c0.w, vb);
        va = fmaf(tb1.x, c1.x, va); vb = fmaf(tb1.y, c1.y, vb);
        va = fmaf(tb1.z, c1.z, va); vb = fmaf(tb1.w, c1.w, vb);
        va = fmaf(tb2.x, c2.x, va); vb = fmaf(tb2.y, c2.y, vb);
        va = fmaf(tb2.z, c2.z, va); vb = fmaf(tb2.w, c2.w, vb);
        va = fmaf(tb3.x, c3.x, va); vb = fmaf(tb3.y, c3.y, vb);
        va = fmaf(tb3.z, c3.z, va); vb = fmaf(tb3.w, c3.w, vb);
        va = fmaf(tb4.x, c4.x, va); vb = fmaf(tb4.y, c4.y, vb);
        va = fmaf(tb4.z, c4.z, va); vb = fmaf(tb4.w, c4.w, vb);
        va = fmaf(tb5.x, c5.x, va); vb = fmaf(tb5.y, c5.y, vb);
        va = fmaf(tb5.z, c5.z, va); vb = fmaf(tb5.w, c5.w, vb);
        va = fmaf(tb6.x, c6.x, va); vb = fmaf(tb6.y, c6.y, vb);
        va = fmaf(tb6.z, c6.z, va); vb = fmaf(tb6.w, c6.w, vb);
        va = fmaf(tb7.x, c7.x, va); vb = fmaf(tb7.y, c7.y, vb);
        va = fmaf(tb7.z, c7.z, va); vb = fmaf(tb7.w, c7.w, vb);

        ((__half2*)(z16 + (size_t)n * (K_OUT * IN_CH)))[l] =
            __floats2half2_rn(ua + ub, va + vb);

        if (!has) break;
        n = nn;
        c0 = p0; c1 = p1; c2 = p2; c3 = p3;
        c4 = p4; c5 = p5; c6 = p6; c7 = p7;
    }
}

// Streaming x -> x16 (fully coalesced, grid-stride; ~9.6MB total traffic).
__global__ __launch_bounds__(256)
void x16_convert_kernel(const float* __restrict__ x,
                        __half* __restrict__ x16,
                        int total4) {
    for (int i = blockIdx.x * blockDim.x + threadIdx.x; i < total4;
         i += gridDim.x * blockDim.x) {
        float4 v = ((const float4*)x)[i];
        __half2 h0 = __floats2half2_rn(v.x, v.y);
        __half2 h1 = __floats2half2_rn(v.z, v.w);
        uint2 pack;
        pack.x = *(unsigned int*)&h0;
        pack.y = *(unsigned int*)&h1;
        ((uint2*)x16)[i] = pack;
    }
}

// ---------------------------------------------------------------------------
// Main edge kernel (unchanged from r9): quad per edge, fp16 operands, fp32
// accumulate. 5 compulsory lines/edge random-gather at the measured
// 3.4-3.9 TB/s random-line fill ceiling. NT hints keep the idx/out streams
// from polluting L2.
// ---------------------------------------------------------------------------
__global__ __launch_bounds__(256)
void edge_kernel_quad16(const __half* __restrict__ x16,
                        const __half* __restrict__ z16,
                        const int* __restrict__ src,
                        const int* __restrict__ dst,
                        float* __restrict__ out,
                        int n_edges) {
    const int t = blockIdx.x * blockDim.x + threadIdx.x;
    const int e = t >> 2;
    const int l = t & 3;
    if (e >= n_edges) return;

    const int s = __builtin_nontemporal_load(src + e);
    const int d = __builtin_nontemporal_load(dst + e);

    const uint4 xv = ((const uint4*)x16)[(size_t)s * 4 + l];
    const uint4* zrow = (const uint4*)z16 + (size_t)d * 16;
    const uint4 z0 = zrow[0 + l];
    const uint4 z1 = zrow[4 + l];
    const uint4 z2 = zrow[8 + l];
    const uint4 z3 = zrow[12 + l];

    float p0 = 0.f, p1 = 0.f, p2 = 0.f, p3 = 0.f;
    p0 = dot2acc(xv.x, z0.x, p0); p0 = dot2acc(xv.y, z0.y, p0);
    p0 = dot2acc(xv.z, z0.z, p0); p0 = dot2acc(xv.w, z0.w, p0);

    p1 = dot2acc(xv.x, z1.x, p1); p1 = dot2acc(xv.y, z1.y, p1);
    p1 = dot2acc(xv.z, z1.z, p1); p1 = dot2acc(xv.w, z1.w, p1);

    p2 = dot2acc(xv.x, z2.x, p2); p2 = dot2acc(xv.y, z2.y, p2);
    p2 = dot2acc(xv.z, z2.z, p2); p2 = dot2acc(xv.w, z2.w, p2);

    p3 = dot2acc(xv.x, z3.x, p3); p3 = dot2acc(xv.y, z3.y, p3);
    p3 = dot2acc(xv.z, z3.z, p3); p3 = dot2acc(xv.w, z3.w, p3);

    float send01 = (l & 1) ? p0 : p1;
    float recv01 = __shfl_xor(send01, 1);
    float a01 = ((l & 1) ? p1 : p0) + recv01;
    float send23 = (l & 1) ? p2 : p3;
    float recv23 = __shfl_xor(send23, 1);
    float a23 = ((l & 1) ? p3 : p2) + recv23;
    float send = (l & 2) ? a01 : a23;
    float recv = __shfl_xor(send, 2);
    float r = ((l & 2) ? a23 : a01) + recv;

    __builtin_nontemporal_store(tanhf(r), out + t);
}

// ---------------------------------------------------------------------------
// Fallback: direct quadratic form per edge (no workspace).
// ---------------------------------------------------------------------------
__global__ void edge_direct_kernel(const float* __restrict__ x,
                                   const float* __restrict__ T,
                                   const int* __restrict__ src,
                                   const int* __restrict__ dst,
                                   float* __restrict__ out,
                                   int n_edges) {
    int e = blockIdx.x * blockDim.x + threadIdx.x;
    if (e >= n_edges) return;

    const int s = src[e];
    const int d = dst[e];

    float xs[IN_CH], xd[IN_CH];
#pragma unroll
    for (int j = 0; j < IN_CH; ++j) {
        xs[j] = x[(size_t)s * IN_CH + j];
        xd[j] = x[(size_t)d * IN_CH + j];
    }

    float resv[K_OUT];
#pragma unroll
    for (int k = 0; k < K_OUT; ++k) {
        float acc = 0.f;
        for (int i = 0; i < IN_CH; ++i) {
            const float* Trow = T + ((size_t)k * IN_CH + i) * IN_CH;
            float yi = 0.f;
#pragma unroll
            for (int j = 0; j < IN_CH; ++j)
                yi = fmaf(Trow[j], xd[j], yi);
            acc = fmaf(xs[i], yi, acc);
        }
        resv[k] = tanhf(acc);
    }
    ((float4*)out)[e] = make_float4(resv[0], resv[1], resv[2], resv[3]);
}

extern "C" void kernel_launch(void* const* d_in, const int* in_sizes, int n_in,
                              void* d_out, int out_size, void* d_ws, size_t ws_size,
                              hipStream_t stream) {
    const float* x  = (const float*)d_in[0];
    const int*   ei = (const int*)d_in[1];
    const float* T  = (const float*)d_in[2];
    float* out      = (float*)d_out;

    const int n_nodes = in_sizes[0] / IN_CH;
    const int n_edges = in_sizes[1] / 2;
    const int* src = ei;
    const int* dst = ei + n_edges;

    // Workspace: z16 then x16 (both 256B-aligned)
    const size_t z16_bytes = (size_t)n_nodes * K_OUT * IN_CH * sizeof(__half);
    const size_t x16_off   = (z16_bytes + 255) & ~(size_t)255;
    const size_t need      = x16_off + (size_t)n_nodes * IN_CH * sizeof(__half);

    const int threads = 256;

    if (ws_size >= need) {
        __half* z16 = (__half*)d_ws;
        __half* x16 = (__half*)((char*)d_ws + x16_off);

        // x16 convert: tiny streaming kernel
        const int total4 = (n_nodes * IN_CH) / 4;
        x16_convert_kernel<<<1024, threads, 0, stream>>>(x, x16, total4);

        // z16: one wave per node, grid-stride, 1-deep row prefetch
        const int pblocks = 1024;                      // 4096 waves
        const int total_waves = pblocks * (threads / 64);
        prep_z_kernel<<<pblocks, threads, 0, stream>>>(x, T, z16, n_nodes, total_waves);

        const long long total = (long long)n_edges * 4;
        const int blocks = (int)((total + threads - 1) / threads);
        edge_kernel_quad16<<<blocks, threads, 0, stream>>>(
            x16, z16, src, dst, out, n_edges);
    } else {
        const int eblocks = (n_edges + threads - 1) / threads;
        edge_direct_kernel<<<eblocks, threads, 0, stream>>>(x, T, src, dst, out, n_edges);
    }
}

// Round 11
// 90.559 us; speedup vs baseline: 1.2387x; 1.1281x over previous
//
#include <hip/hip_runtime.h>
#include <hip/hip_fp16.h>
#include <math.h>

#define IN_CH 32
#define K_OUT 4
#define KI (K_OUT * IN_CH)        // 128 outputs per node
#define BATCH_NODES 8             // nodes staged per wave-batch (1KB)
#define BATCH_FLOATS (BATCH_NODES * IN_CH)   // 256

typedef _Float16 h2_t __attribute__((ext_vector_type(2)));

// fp16x2 dot with fp32 accumulate: uses v_dot2_f32_f16 when available.
__device__ __forceinline__ float dot2acc(unsigned int a, unsigned int b, float c) {
#if defined(__has_builtin)
#if __has_builtin(__builtin_amdgcn_fdot2)
    return __builtin_amdgcn_fdot2(__builtin_bit_cast(h2_t, a),
                                  __builtin_bit_cast(h2_t, b), c, false);
#else
    __half2 ha = *(__half2*)&a, hb = *(__half2*)&b;
    float2 fa = __half22float2(ha), fb = __half22float2(hb);
    return fmaf(fa.y, fb.y, fmaf(fa.x, fb.x, c));
#endif
#else
    __half2 ha = *(__half2*)&a, hb = *(__half2*)&b;
    float2 fa = __half22float2(ha), fb = __half22float2(hb);
    return fmaf(fa.y, fb.y, fmaf(fa.x, fb.x, c));
#endif
}

// ---------------------------------------------------------------------------
// Prep v5 (r8-r10 lesson: wave-uniform global loads scalarize to in-order
// SMEM and serialize ~500cy each; ALL global access here is lane-varying
// and coalesced).
//  - Wave grabs a batch of 8 contiguous node rows: lane l loads float4 #l of
//    the 1KB slab (coalesced), prefetched one batch ahead in registers.
//  - x16 is converted from those same registers (free) -> no separate kernel.
//  - Slab goes to LDS; compute: lane l owns T rows 4*(l&31)..+3 (128 VGPRs),
//    lanes 0-31 do node 2p, lanes 32-63 node 2p+1 -> each ds_read_b128 is a
//    2-address broadcast (2-way = free, m136).
//  - Stores: z16 row = 32 x uint2 per half-wave (256B coalesced).
// ---------------------------------------------------------------------------
__global__ __launch_bounds__(128)
void prep_kernel(const float* __restrict__ x,
                 const float* __restrict__ T,
                 __half* __restrict__ z16,
                 __half* __restrict__ x16,
                 int n_nodes, int total_waves) {
    __shared__ float lds[2][BATCH_FLOATS];   // [wave-in-block][256 floats]
    const int wv = threadIdx.x >> 6;
    const int l  = threadIdx.x & 63;
    const int gwave = (blockIdx.x * (blockDim.x >> 6)) + wv;

    // ---- T rows -> 128 VGPRs: lane covers ki = 4*(l&31) + r ----
    const int kbase = (l & 31) * 4;
    float tr[4][IN_CH];
#pragma unroll
    for (int r = 0; r < 4; ++r) {
        const float4* Tp = (const float4*)(T + (size_t)(kbase + r) * IN_CH);
#pragma unroll
        for (int q = 0; q < 8; ++q) {
            float4 v = Tp[q];
            tr[r][q * 4 + 0] = v.x; tr[r][q * 4 + 1] = v.y;
            tr[r][q * 4 + 2] = v.z; tr[r][q * 4 + 3] = v.w;
        }
    }

    const long long ftotal = (long long)n_nodes * IN_CH;
    const int n_batches = (n_nodes + BATCH_NODES - 1) / BATCH_NODES;

    int b = gwave;
    if (b >= n_batches) return;

    // preload batch b (coalesced float4/lane; clamp tail)
    long long fidx = (long long)b * BATCH_FLOATS + l * 4;
    long long fclamp = fidx + 4 > ftotal ? ftotal - 4 : fidx;
    float4 stg = *(const float4*)(x + fclamp);
    bool st_ok = (fidx == fclamp);

    while (true) {
        // stage current batch into LDS (same-wave write->read, compiler orders)
        ((float4*)lds[wv])[l] = stg;

        // x16 convert straight from the staged registers (coalesced 8B store)
        if (st_ok) {
            __half2 h0 = __floats2half2_rn(stg.x, stg.y);
            __half2 h1 = __floats2half2_rn(stg.z, stg.w);
            uint2 pk;
            pk.x = *(unsigned int*)&h0;
            pk.y = *(unsigned int*)&h1;
            *(uint2*)(x16 + fidx) = pk;
        }

        // prefetch next batch (lane-varying vector load: pipelines under compute)
        const int bn = b + total_waves;
        if (bn < n_batches) {
            fidx = (long long)bn * BATCH_FLOATS + l * 4;
            fclamp = fidx + 4 > ftotal ? ftotal - 4 : fidx;
            stg = *(const float4*)(x + fclamp);
            st_ok = (fidx == fclamp);
        }

        // compute 4 node-pairs from the staged slab
#pragma unroll
        for (int p = 0; p < 4; ++p) {
            const int lrow = p * 2 + (l >> 5);          // 0..7 within batch
            const int node = b * BATCH_NODES + lrow;
            const float4* xrow = (const float4*)(lds[wv] + lrow * IN_CH);

            float a0 = 0.f, a1 = 0.f, a2 = 0.f, a3 = 0.f;
#pragma unroll
            for (int q = 0; q < 8; ++q) {
                float4 xq = xrow[q];                    // 2-addr broadcast b128
                a0 = fmaf(tr[0][q*4+0], xq.x, a0); a0 = fmaf(tr[0][q*4+1], xq.y, a0);
                a0 = fmaf(tr[0][q*4+2], xq.z, a0); a0 = fmaf(tr[0][q*4+3], xq.w, a0);
                a1 = fmaf(tr[1][q*4+0], xq.x, a1); a1 = fmaf(tr[1][q*4+1], xq.y, a1);
                a1 = fmaf(tr[1][q*4+2], xq.z, a1); a1 = fmaf(tr[1][q*4+3], xq.w, a1);
                a2 = fmaf(tr[2][q*4+0], xq.x, a2); a2 = fmaf(tr[2][q*4+1], xq.y, a2);
                a2 = fmaf(tr[2][q*4+2], xq.z, a2); a2 = fmaf(tr[2][q*4+3], xq.w, a2);
                a3 = fmaf(tr[3][q*4+0], xq.x, a3); a3 = fmaf(tr[3][q*4+1], xq.y, a3);
                a3 = fmaf(tr[3][q*4+2], xq.z, a3); a3 = fmaf(tr[3][q*4+3], xq.w, a3);
            }

            if (node < n_nodes) {
                __half2 ha = __floats2half2_rn(a0, a1);
                __half2 hb = __floats2half2_rn(a2, a3);
                uint2 pk;
                pk.x = *(unsigned int*)&ha;
                pk.y = *(unsigned int*)&hb;
                *(uint2*)(z16 + (size_t)node * KI + kbase) = pk;  // 256B/half-wave
            }
        }

        if (bn >= n_batches) break;
        b = bn;
    }
}

// ---------------------------------------------------------------------------
// Main edge kernel (unchanged; at measured ceiling): quad per edge, fp16
// operands, fp32 accumulate. 5 compulsory lines/edge random-gather at the
// 3.4-3.9 TB/s random-line fill ceiling. NT hints keep idx/out streams from
// polluting L2.
// ---------------------------------------------------------------------------
__global__ __launch_bounds__(256)
void edge_kernel_quad16(const __half* __restrict__ x16,
                        const __half* __restrict__ z16,
                        const int* __restrict__ src,
                        const int* __restrict__ dst,
                        float* __restrict__ out,
                        int n_edges) {
    const int t = blockIdx.x * blockDim.x + threadIdx.x;
    const int e = t >> 2;
    const int l = t & 3;
    if (e >= n_edges) return;

    const int s = __builtin_nontemporal_load(src + e);
    const int d = __builtin_nontemporal_load(dst + e);

    const uint4 xv = ((const uint4*)x16)[(size_t)s * 4 + l];
    const uint4* zrow = (const uint4*)z16 + (size_t)d * 16;
    const uint4 z0 = zrow[0 + l];
    const uint4 z1 = zrow[4 + l];
    const uint4 z2 = zrow[8 + l];
    const uint4 z3 = zrow[12 + l];

    float p0 = 0.f, p1 = 0.f, p2 = 0.f, p3 = 0.f;
    p0 = dot2acc(xv.x, z0.x, p0); p0 = dot2acc(xv.y, z0.y, p0);
    p0 = dot2acc(xv.z, z0.z, p0); p0 = dot2acc(xv.w, z0.w, p0);

    p1 = dot2acc(xv.x, z1.x, p1); p1 = dot2acc(xv.y, z1.y, p1);
    p1 = dot2acc(xv.z, z1.z, p1); p1 = dot2acc(xv.w, z1.w, p1);

    p2 = dot2acc(xv.x, z2.x, p2); p2 = dot2acc(xv.y, z2.y, p2);
    p2 = dot2acc(xv.z, z2.z, p2); p2 = dot2acc(xv.w, z2.w, p2);

    p3 = dot2acc(xv.x, z3.x, p3); p3 = dot2acc(xv.y, z3.y, p3);
    p3 = dot2acc(xv.z, z3.z, p3); p3 = dot2acc(xv.w, z3.w, p3);

    float send01 = (l & 1) ? p0 : p1;
    float recv01 = __shfl_xor(send01, 1);
    float a01 = ((l & 1) ? p1 : p0) + recv01;
    float send23 = (l & 1) ? p2 : p3;
    float recv23 = __shfl_xor(send23, 1);
    float a23 = ((l & 1) ? p3 : p2) + recv23;
    float send = (l & 2) ? a01 : a23;
    float recv = __shfl_xor(send, 2);
    float r = ((l & 2) ? a23 : a01) + recv;

    __builtin_nontemporal_store(tanhf(r), out + t);
}

// ---------------------------------------------------------------------------
// Fallback: direct quadratic form per edge (no workspace).
// ---------------------------------------------------------------------------
__global__ void edge_direct_kernel(const float* __restrict__ x,
                                   const float* __restrict__ T,
                                   const int* __restrict__ src,
                                   const int* __restrict__ dst,
                                   float* __restrict__ out,
                                   int n_edges) {
    int e = blockIdx.x * blockDim.x + threadIdx.x;
    if (e >= n_edges) return;

    const int s = src[e];
    const int d = dst[e];

    float xs[IN_CH], xd[IN_CH];
#pragma unroll
    for (int j = 0; j < IN_CH; ++j) {
        xs[j] = x[(size_t)s * IN_CH + j];
        xd[j] = x[(size_t)d * IN_CH + j];
    }

    float resv[K_OUT];
#pragma unroll
    for (int k = 0; k < K_OUT; ++k) {
        float acc = 0.f;
        for (int i = 0; i < IN_CH; ++i) {
            const float* Trow = T + ((size_t)k * IN_CH + i) * IN_CH;
            float yi = 0.f;
#pragma unroll
            for (int j = 0; j < IN_CH; ++j)
                yi = fmaf(Trow[j], xd[j], yi);
            acc = fmaf(xs[i], yi, acc);
        }
        resv[k] = tanhf(acc);
    }
    ((float4*)out)[e] = make_float4(resv[0], resv[1], resv[2], resv[3]);
}

extern "C" void kernel_launch(void* const* d_in, const int* in_sizes, int n_in,
                              void* d_out, int out_size, void* d_ws, size_t ws_size,
                              hipStream_t stream) {
    const float* x  = (const float*)d_in[0];
    const int*   ei = (const int*)d_in[1];
    const float* T  = (const float*)d_in[2];
    float* out      = (float*)d_out;

    const int n_nodes = in_sizes[0] / IN_CH;
    const int n_edges = in_sizes[1] / 2;
    const int* src = ei;
    const int* dst = ei + n_edges;

    // Workspace: z16 then x16 (both 256B-aligned)
    const size_t z16_bytes = (size_t)n_nodes * KI * sizeof(__half);
    const size_t x16_off   = (z16_bytes + 255) & ~(size_t)255;
    const size_t need      = x16_off + (size_t)n_nodes * IN_CH * sizeof(__half);

    const int threads = 256;

    if (ws_size >= need && n_nodes >= BATCH_NODES) {
        __half* z16 = (__half*)d_ws;
        __half* x16 = (__half*)((char*)d_ws + x16_off);

        // prep: 1024 blocks x 128 thr = 2048 waves, grid-stride over batches
        const int pblocks = 1024;
        const int total_waves = pblocks * 2;
        prep_kernel<<<pblocks, 128, 0, stream>>>(x, T, z16, x16, n_nodes, total_waves);

        const long long total = (long long)n_edges * 4;
        const int blocks = (int)((total + threads - 1) / threads);
        edge_kernel_quad16<<<blocks, threads, 0, stream>>>(
            x16, z16, src, dst, out, n_edges);
    } else {
        const int eblocks = (n_edges + threads - 1) / threads;
        edge_direct_kernel<<<eblocks, threads, 0, stream>>>(x, T, src, dst, out, n_edges);
    }
}